// Round 8
// baseline (208.523 us; speedup 1.0000x reference)
//
#include <hip/hip_runtime.h>

#define EPS 1e-8f
#define LAM 0.01f

constexpr int BS = 256;
constexpr int L  = 2048;
constexpr int N  = 128;
constexpr int CHUNK  = 128;          // rows per block; 8 groups x 16 consecutive rows
constexpr int NCHUNK = L / CHUNK;    // 16
constexpr int REPEAT = 4;            // instrumentation: x4 passes to surface counters

typedef float v4f __attribute__((ext_vector_type(4)));

// ws layout (float indices):
//   [0         .. BS*NCHUNK)    = S1 partial per (batch, chunk)
//   [BS*NCHUNK .. 2*BS*NCHUNK)  = S2 partial per (batch, chunk)
// Blocks write only live chunks; finalize reads only live chunks, so no
// pre-zeroing is needed and every replay rewrites the same slots.

__device__ __forceinline__ v4f ld4(const float* p) {
    return *reinterpret_cast<const v4f*>(p);
}

__device__ __forceinline__ float rowdot(const v4f wv, const v4f pi, const v4f pj) {
    float acc = 0.0f;
    #pragma unroll
    for (int i = 0; i < 4; ++i) {
        float r = (pj[i] - pi[i]) * __builtin_amdgcn_rcpf(pi[i]);
        r = (r <= 2.0f) ? r : 0.0f;
        acc += wv[i] * r;
    }
    return acc;
}

__global__ __launch_bounds__(256) void rp_kernel(
    const float* __restrict__ w,      // [BS][L][N]
    const float* __restrict__ price,  // [BS][L+1][N]
    const int*  __restrict__ pred_sz, // [BS]
    float* __restrict__ ws)
{
    const int b     = blockIdx.x / NCHUNK;
    const int chunk = blockIdx.x % NCHUNK;
    const int n     = pred_sz[b];

    const int start = chunk * CHUNK;
    if (start >= n) return;                 // dead block: no loads, no writes
    const int end = min(start + CHUNK, n);

    const int tid  = threadIdx.x;
    const int grp  = tid >> 5;
    const int lane = tid & 31;

    const int rs = start + grp * 16;        // this group's 16 consecutive rows
    const int re = min(rs + 16, end);

    __shared__ float ls1[8], ls2[8];

    // Instrumentation: repeat the full computation REPEAT times. Every pass
    // recomputes identical values and rewrites the same ws slots, so output
    // is unchanged; the repeats make rp_kernel's duration exceed the harness
    // fill kernels so its counters appear in the profile top-5.
    for (int pass = 0; pass < REPEAT; ++pass) {
        float s1 = 0.0f, s2 = 0.0f;

        if (re - rs == 16) {
            // ---- fast path: 16 full rows, price row carried in registers ----
            const float* wp = w     + ((size_t)b * L       + rs) * N + lane * 4;
            const float* pp = price + ((size_t)b * (L + 1) + rs) * N + lane * 4;

            v4f pv = ld4(pp);                    // price row rs
            #pragma unroll
            for (int half = 0; half < 2; ++half) {
                float A[8];
                #pragma unroll
                for (int r = 0; r < 8; ++r) {
                    const int rr = half * 8 + r;
                    const v4f pj = ld4(pp + (size_t)(rr + 1) * N);
                    const v4f wv = ld4(wp + (size_t)rr * N);
                    A[r] = rowdot(wv, pv, pj);
                    pv = pj;                     // row rr's P_j is row rr+1's P_i
                }
                // Butterfly transpose-reduce over 8 rows x 32 lanes.
                #pragma unroll
                for (int k = 0; k < 3; ++k) {
                    const int  m  = 1 << k;
                    const bool hi = (lane & m) != 0;
                    #pragma unroll
                    for (int t = 0; t < (4 >> k); ++t) {
                        const float send = hi ? A[2 * t] : A[2 * t + 1];
                        const float recv = __shfl_xor(send, m);
                        A[t] = (hi ? A[2 * t + 1] : A[2 * t]) + recv;
                    }
                }
                float v = A[0] + __shfl_xor(A[0], 8);
                v += __shfl_xor(v, 16);
                const float vm = ((lane & 24) == 0) ? v : 0.0f;  // keep 1 of 4 copies
                s1 += vm;
                s2 += vm * vm;
            }
        } else if (rs < end) {
            // ---- tail path: < 16 rows (at most one group per batch) ----
            const float* wp = w     + ((size_t)b * L       + rs) * N + lane * 4;
            const float* pp = price + ((size_t)b * (L + 1) + rs) * N + lane * 4;
            for (int l = rs; l < re; ++l, wp += N, pp += N) {
                const v4f pi = ld4(pp);
                const v4f pj = ld4(pp + N);
                const v4f wv = ld4(wp);
                float acc = rowdot(wv, pi, pj);
                #pragma unroll
                for (int m = 1; m < 32; m <<= 1)
                    acc += __shfl_xor(acc, m);
                if (lane == 0) { s1 += acc; s2 += acc * acc; }
            }
        }

        // Reduce s1/s2 across group, then across the 8 groups.
        #pragma unroll
        for (int m = 1; m < 32; m <<= 1) {
            s1 += __shfl_xor(s1, m);
            s2 += __shfl_xor(s2, m);
        }
        if (lane == 0) { ls1[grp] = s1; ls2[grp] = s2; }
        __syncthreads();
        if (tid == 0) {
            float t1 = 0.0f, t2 = 0.0f;
            #pragma unroll
            for (int i = 0; i < 8; ++i) { t1 += ls1[i]; t2 += ls2[i]; }
            ws[b * NCHUNK + chunk]               = t1;
            ws[BS * NCHUNK + b * NCHUNK + chunk] = t2;
        }
        __syncthreads();                      // ls reuse + pass separation
        asm volatile("" ::: "memory");        // no cross-pass CSE of the loads
    }
}

__global__ __launch_bounds__(256) void final_kernel(
    const float* __restrict__ ws,
    const int*  __restrict__ pred_sz,
    float* __restrict__ out)
{
    const int b = threadIdx.x;   // 256 threads, one per batch
    const int ni = pred_sz[b];
    const int nc = (ni + CHUNK - 1) / CHUNK;   // live chunks for this batch

    float s1 = 0.0f, s2 = 0.0f;
    for (int c = 0; c < nc; ++c) {
        s1 += ws[b * NCHUNK + c];
        s2 += ws[BS * NCHUNK + b * NCHUNK + c];
    }

    const float n     = (float)ni;
    const float E     = s1 / n;
    const float var   = (s2 - n * E * E) / (n - 1.0f);
    const float denom = sqrtf(var + EPS);
    const float sharpe      = E / denom;
    const float sharpe_list = E - LAM / denom;

    __shared__ float red[4][BS];
    red[0][b] = sharpe_list;
    red[1][b] = sharpe;
    red[2][b] = E;
    red[3][b] = var;
    __syncthreads();

    #pragma unroll
    for (int s = BS / 2; s > 0; s >>= 1) {
        if (b < s) {
            red[0][b] += red[0][b + s];
            red[1][b] += red[1][b + s];
            red[2][b] += red[2][b + s];
            red[3][b] += red[3][b + s];
        }
        __syncthreads();
    }

    if (b == 0) {
        out[0] = -red[0][0] / (float)BS;
        out[1] = -red[1][0] / (float)BS;
        out[2] =  red[2][0] / (float)BS;
        out[3] =  red[3][0] / (float)BS;
    }
}

extern "C" void kernel_launch(void* const* d_in, const int* in_sizes, int n_in,
                              void* d_out, int out_size, void* d_ws, size_t ws_size,
                              hipStream_t stream) {
    const float* w     = (const float*)d_in[0];  // pred_weights [256][2048][128]
    const float* price = (const float*)d_in[1];  // price_list   [256][2049][128]
    const int*   psz   = (const int*)d_in[2];    // pred_sz      [256]
    float* out = (float*)d_out;
    float* ws  = (float*)d_ws;

    rp_kernel<<<BS * NCHUNK, 256, 0, stream>>>(w, price, psz, ws);
    final_kernel<<<1, BS, 0, stream>>>(ws, psz, out);
}

// Round 9
// 104.786 us; speedup vs baseline: 1.9900x; 1.9900x over previous
//
#include <hip/hip_runtime.h>

#define EPS 1e-8f
#define LAM 0.01f

constexpr int BS = 256;
constexpr int L  = 2048;
constexpr int N  = 128;
constexpr int CHUNK  = 128;          // rows per tile; 8 groups x 16 consecutive rows
constexpr int NCHUNK = L / CHUNK;    // 16
constexpr int NT     = BS * NCHUNK;  // 4096 tiles
constexpr int GRID   = 2048;         // 8 blocks/CU x 256 CU: whole grid resident at t=0

typedef float v4f __attribute__((ext_vector_type(4)));

// ws layout (float indices):
//   [0   .. NT)    S1 partial per tile t = b*NCHUNK + chunk
//   [NT  .. 2*NT)  S2 partial per tile
//   [2*NT]         int work-stealing counter (reset by captured memset each call)
// Live-tile slots are fully rewritten every call; dead slots are never read.

__device__ __forceinline__ v4f ld4(const float* p) {
    return *reinterpret_cast<const v4f*>(p);
}

__device__ __forceinline__ float rowdot(const v4f wv, const v4f pi, const v4f pj) {
    float acc = 0.0f;
    #pragma unroll
    for (int i = 0; i < 4; ++i) {
        float r = (pj[i] - pi[i]) * __builtin_amdgcn_rcpf(pi[i]);
        r = (r <= 2.0f) ? r : 0.0f;
        acc += wv[i] * r;
    }
    return acc;
}

__global__ __launch_bounds__(256) void rp_kernel(
    const float* __restrict__ w,      // [BS][L][N]
    const float* __restrict__ price,  // [BS][L+1][N]
    const int*  __restrict__ pred_sz, // [BS]
    float* __restrict__ ws)
{
    int* cnt = (int*)(ws + 2 * NT);
    const int tid  = threadIdx.x;
    const int grp  = tid >> 5;
    const int lane = tid & 31;

    __shared__ float ls1[8], ls2[8];
    __shared__ int s_t;

    for (;;) {
        // grab next tile (barrier also protects s_t/ls reuse across iterations)
        __syncthreads();
        if (tid == 0) s_t = atomicAdd(cnt, 1);
        __syncthreads();
        const int t = s_t;
        if (t >= NT) return;

        const int b     = t >> 4;            // NCHUNK == 16
        const int chunk = t & 15;
        const int n     = pred_sz[b];
        const int start = chunk * CHUNK;
        if (start >= n) continue;            // dead tile: ~zero cost
        const int end = min(start + CHUNK, n);

        const int rs = start + grp * 16;     // this group's 16 consecutive rows
        const int re = min(rs + 16, end);

        float s1 = 0.0f, s2 = 0.0f;

        if (re - rs == 16) {
            // ---- fast path: 16 full rows, price row carried in registers ----
            const float* wp = w     + ((size_t)b * L       + rs) * N + lane * 4;
            const float* pp = price + ((size_t)b * (L + 1) + rs) * N + lane * 4;

            v4f pv = ld4(pp);                    // price row rs
            #pragma unroll
            for (int half = 0; half < 2; ++half) {
                float A[8];
                #pragma unroll
                for (int r = 0; r < 8; ++r) {
                    const int rr = half * 8 + r;
                    const v4f pj = ld4(pp + (size_t)(rr + 1) * N);
                    const v4f wv = ld4(wp + (size_t)rr * N);
                    A[r] = rowdot(wv, pv, pj);
                    pv = pj;                     // row rr's P_j is row rr+1's P_i
                }
                // Butterfly transpose-reduce over 8 rows x 32 lanes.
                #pragma unroll
                for (int k = 0; k < 3; ++k) {
                    const int  m  = 1 << k;
                    const bool hi = (lane & m) != 0;
                    #pragma unroll
                    for (int u = 0; u < (4 >> k); ++u) {
                        const float send = hi ? A[2 * u] : A[2 * u + 1];
                        const float recv = __shfl_xor(send, m);
                        A[u] = (hi ? A[2 * u + 1] : A[2 * u]) + recv;
                    }
                }
                float v = A[0] + __shfl_xor(A[0], 8);
                v += __shfl_xor(v, 16);
                const float vm = ((lane & 24) == 0) ? v : 0.0f;  // keep 1 of 4 copies
                s1 += vm;
                s2 += vm * vm;
            }
        } else if (rs < end) {
            // ---- tail path: < 16 rows (at most one group per batch) ----
            const float* wp = w     + ((size_t)b * L       + rs) * N + lane * 4;
            const float* pp = price + ((size_t)b * (L + 1) + rs) * N + lane * 4;
            for (int l = rs; l < re; ++l, wp += N, pp += N) {
                const v4f pi = ld4(pp);
                const v4f pj = ld4(pp + N);
                const v4f wv = ld4(wp);
                float acc = rowdot(wv, pi, pj);
                #pragma unroll
                for (int m = 1; m < 32; m <<= 1)
                    acc += __shfl_xor(acc, m);
                if (lane == 0) { s1 += acc; s2 += acc * acc; }
            }
        }

        // Reduce s1/s2 across group, then across the 8 groups.
        #pragma unroll
        for (int m = 1; m < 32; m <<= 1) {
            s1 += __shfl_xor(s1, m);
            s2 += __shfl_xor(s2, m);
        }
        if (lane == 0) { ls1[grp] = s1; ls2[grp] = s2; }
        __syncthreads();
        if (tid == 0) {
            float t1 = 0.0f, t2 = 0.0f;
            #pragma unroll
            for (int i = 0; i < 8; ++i) { t1 += ls1[i]; t2 += ls2[i]; }
            ws[t]      = t1;
            ws[NT + t] = t2;
        }
    }
}

__global__ __launch_bounds__(64) void final_kernel(
    const float* __restrict__ ws,
    const int*  __restrict__ pred_sz,
    float* __restrict__ out)
{
    const int lane = threadIdx.x;    // one wave; 4 batches per lane
    float a0 = 0.0f, a1 = 0.0f, a2 = 0.0f, a3 = 0.0f;

    #pragma unroll
    for (int k = 0; k < 4; ++k) {
        const int b  = lane + 64 * k;
        const int ni = pred_sz[b];
        const int nc = (ni + CHUNK - 1) / CHUNK;     // live tiles for this batch

        float s1 = 0.0f, s2 = 0.0f;
        for (int c = 0; c < nc; ++c) {
            s1 += ws[b * NCHUNK + c];
            s2 += ws[NT + b * NCHUNK + c];
        }
        const float n     = (float)ni;
        const float E     = s1 / n;
        const float var   = (s2 - n * E * E) / (n - 1.0f);
        const float denom = sqrtf(var + EPS);
        a0 += E - LAM / denom;       // sharpe_list
        a1 += E / denom;             // sharpe
        a2 += E;
        a3 += var;
    }

    #pragma unroll
    for (int m = 1; m < 64; m <<= 1) {
        a0 += __shfl_xor(a0, m);
        a1 += __shfl_xor(a1, m);
        a2 += __shfl_xor(a2, m);
        a3 += __shfl_xor(a3, m);
    }
    if (lane == 0) {
        out[0] = -a0 / (float)BS;
        out[1] = -a1 / (float)BS;
        out[2] =  a2 / (float)BS;
        out[3] =  a3 / (float)BS;
    }
}

extern "C" void kernel_launch(void* const* d_in, const int* in_sizes, int n_in,
                              void* d_out, int out_size, void* d_ws, size_t ws_size,
                              hipStream_t stream) {
    const float* w     = (const float*)d_in[0];  // pred_weights [256][2048][128]
    const float* price = (const float*)d_in[1];  // price_list   [256][2049][128]
    const int*   psz   = (const int*)d_in[2];    // pred_sz      [256]
    float* out = (float*)d_out;
    float* ws  = (float*)d_ws;

    // Reset the work-stealing counter (captured as a memset node).
    hipMemsetAsync((char*)d_ws + (size_t)2 * NT * sizeof(float), 0,
                   sizeof(int), stream);
    rp_kernel<<<GRID, 256, 0, stream>>>(w, price, psz, ws);
    final_kernel<<<1, 64, 0, stream>>>(ws, psz, out);
}

// Round 10
// 70.608 us; speedup vs baseline: 2.9533x; 1.4841x over previous
//
#include <hip/hip_runtime.h>

#define EPS 1e-8f
#define LAM 0.01f

constexpr int BS = 256;
constexpr int L  = 2048;
constexpr int N  = 128;
constexpr int CHUNK  = 128;            // rows per block
constexpr int NCHUNK = L / CHUNK;      // 16
constexpr int SUB    = 16;             // rows per staged subtile
constexpr int NSUBMX = CHUNK / SUB;    // 8 subtiles per block
constexpr int PBUF   = 9 * 256;        // price LDS buffer floats (9 KB; holds 17 rows + pad)

typedef float v4f __attribute__((ext_vector_type(4)));

// ws layout (float indices):
//   [0         .. BS*NCHUNK)    = S1 partial per (batch, chunk)
//   [BS*NCHUNK .. 2*BS*NCHUNK)  = S2 partial per (batch, chunk)
// Live slots fully rewritten each call; dead slots never read. No pre-zeroing.

__device__ __forceinline__ v4f ld4(const float* p) {
    return *reinterpret_cast<const v4f*>(p);
}

__device__ __forceinline__ float rowdot(const v4f wv, const v4f pi, const v4f pj) {
    float acc = 0.0f;
    #pragma unroll
    for (int i = 0; i < 4; ++i) {
        float r = (pj[i] - pi[i]) * __builtin_amdgcn_rcpf(pi[i]);
        r = (r <= 2.0f) ? r : 0.0f;
        acc += wv[i] * r;
    }
    return acc;
}

#define GLDS(gsrc, ldst) \
    __builtin_amdgcn_global_load_lds( \
        (const __attribute__((address_space(1))) void*)(gsrc), \
        (__attribute__((address_space(3))) void*)(ldst), 16, 0, 0)

__global__ __launch_bounds__(256) void rp_kernel(
    const float* __restrict__ w,      // [BS][L][N]
    const float* __restrict__ price,  // [BS][L+1][N]
    const int*  __restrict__ pred_sz, // [BS]
    float* __restrict__ ws)
{
    const int b     = blockIdx.x / NCHUNK;
    const int chunk = blockIdx.x % NCHUNK;
    const int n     = pred_sz[b];

    const int start = chunk * CHUNK;
    if (start >= n) return;                  // dead block: no loads, no barriers
    const int live = min(start + CHUNK, n) - start;
    const int ns   = (live + SUB - 1) / SUB; // live subtiles, uniform per block

    const int tid   = threadIdx.x;
    const int wid   = tid >> 6;    // wave 0..3
    const int wlane = tid & 63;
    const int grp   = tid >> 5;    // 32-lane group 0..7
    const int lane  = tid & 31;

    __shared__ float lw[2][SUB * N];   // 8 KB per buffer
    __shared__ float lp[2][PBUF];      // 9 KB per buffer (17 rows + pad)
    __shared__ float ls1[8], ls2[8];

    const float* wbase = w     + ((size_t)b * L       + start) * N;
    const float* pbase = price + ((size_t)b * (L + 1) + start) * N;
    const float* pend  = price + (size_t)BS * (L + 1) * N;   // allocation end

    // Stage subtile k into buffers k&1 via DMA (global_load_lds):
    //   w rows [k*16, k*16+16)  -> lw : 8 x 1KB wave-writes (2 per wave)
    //   p rows [k*16, k*16+17)  -> lp : 9 x 1KB wave-writes (2 per wave + 1 on wave 0)
    // Per-wave issue count: wave0 = 5, waves 1-3 = 4.
    auto STAGE = [&](int k) {
        const int bi = k & 1;
        const float* wsrc = wbase + (size_t)k * SUB * N;
        const float* psrc = pbase + (size_t)k * SUB * N;
        #pragma unroll
        for (int u = 0; u < 2; ++u) {
            const int j = 2 * wid + u;       // 1-KB unit index 0..7
            GLDS(wsrc + j * 256 + wlane * 4, &lw[bi][j * 256]);
            GLDS(psrc + j * 256 + wlane * 4, &lp[bi][j * 256]);
        }
        if (wid == 0) {                      // 9th price write (rows 16-17); clamp vs alloc end
            const float* ps = psrc + 8 * 256 + wlane * 4;
            if (ps + 4 > pend) ps = pend - 4;          // garbage-but-unused pad rows
            GLDS(ps, &lp[bi][8 * 256]);
        }
    };

    STAGE(0);
    if (ns > 1) STAGE(1);

    float s1 = 0.0f, s2 = 0.0f;

    for (int k = 0; k < ns; ++k) {
        // Wait for stage k only (leave stage k+1 in flight) — counted vmcnt.
        if (k + 1 < ns) {
            if (wid == 0) asm volatile("s_waitcnt vmcnt(5)" ::: "memory");
            else          asm volatile("s_waitcnt vmcnt(4)" ::: "memory");
        } else {
            asm volatile("s_waitcnt vmcnt(0)" ::: "memory");
        }
        __builtin_amdgcn_sched_barrier(0);
        __builtin_amdgcn_s_barrier();        // all waves' stage-k DMA complete

        // ---- compute subtile k from LDS: group handles local rows 2g, 2g+1 ----
        {
            const int bi  = k & 1;
            const int off = (2 * grp) * N + lane * 4;
            const v4f pi0 = ld4(&lp[bi][off]);
            const v4f pm  = ld4(&lp[bi][off + N]);
            const v4f pj1 = ld4(&lp[bi][off + 2 * N]);   // grp7 reads staged row 16
            const v4f wv0 = ld4(&lw[bi][off]);
            const v4f wv1 = ld4(&lw[bi][off + N]);

            const int lrow = k * SUB + 2 * grp;
            float A0 = (lrow     < live) ? rowdot(wv0, pi0, pm)  : 0.0f;
            float A1 = (lrow + 1 < live) ? rowdot(wv1, pm, pj1) : 0.0f;

            // pairwise exchange on lane bit0: v = row(lane&1) partial over pair
            const bool hi   = (lane & 1) != 0;
            const float send = hi ? A0 : A1;
            const float recv = __shfl_xor(send, 1);
            float v = (hi ? A1 : A0) + recv;
            v += __shfl_xor(v, 2);
            v += __shfl_xor(v, 4);
            v += __shfl_xor(v, 8);
            v += __shfl_xor(v, 16);
            // lane0 holds row(2g) sum, lane1 holds row(2g+1) sum
            const float vm = (lane < 2) ? v : 0.0f;
            s1 += vm;
            s2 += vm * vm;
        }

        asm volatile("s_waitcnt lgkmcnt(0)" ::: "memory");
        __builtin_amdgcn_sched_barrier(0);
        __builtin_amdgcn_s_barrier();        // all waves done reading buf k&1

        if (k + 2 < ns) STAGE(k + 2);        // refill the buffer just freed
    }

    // ---- block reduction of s1/s2 ----
    #pragma unroll
    for (int m = 1; m < 32; m <<= 1) {
        s1 += __shfl_xor(s1, m);
        s2 += __shfl_xor(s2, m);
    }
    if (lane == 0) { ls1[grp] = s1; ls2[grp] = s2; }
    __syncthreads();
    if (tid == 0) {
        float t1 = 0.0f, t2 = 0.0f;
        #pragma unroll
        for (int i = 0; i < 8; ++i) { t1 += ls1[i]; t2 += ls2[i]; }
        ws[b * NCHUNK + chunk]               = t1;
        ws[BS * NCHUNK + b * NCHUNK + chunk] = t2;
    }
}

__global__ __launch_bounds__(64) void final_kernel(
    const float* __restrict__ ws,
    const int*  __restrict__ pred_sz,
    float* __restrict__ out)
{
    const int lane = threadIdx.x;    // one wave; 4 batches per lane
    float a0 = 0.0f, a1 = 0.0f, a2 = 0.0f, a3 = 0.0f;

    #pragma unroll
    for (int k = 0; k < 4; ++k) {
        const int b  = lane + 64 * k;
        const int ni = pred_sz[b];
        const int nc = (ni + CHUNK - 1) / CHUNK;

        float s1 = 0.0f, s2 = 0.0f;
        for (int c = 0; c < nc; ++c) {
            s1 += ws[b * NCHUNK + c];
            s2 += ws[BS * NCHUNK + b * NCHUNK + c];
        }
        const float n     = (float)ni;
        const float E     = s1 / n;
        const float var   = (s2 - n * E * E) / (n - 1.0f);
        const float denom = sqrtf(var + EPS);
        a0 += E - LAM / denom;       // sharpe_list
        a1 += E / denom;             // sharpe
        a2 += E;
        a3 += var;
    }

    #pragma unroll
    for (int m = 1; m < 64; m <<= 1) {
        a0 += __shfl_xor(a0, m);
        a1 += __shfl_xor(a1, m);
        a2 += __shfl_xor(a2, m);
        a3 += __shfl_xor(a3, m);
    }
    if (lane == 0) {
        out[0] = -a0 / (float)BS;
        out[1] = -a1 / (float)BS;
        out[2] =  a2 / (float)BS;
        out[3] =  a3 / (float)BS;
    }
}

extern "C" void kernel_launch(void* const* d_in, const int* in_sizes, int n_in,
                              void* d_out, int out_size, void* d_ws, size_t ws_size,
                              hipStream_t stream) {
    const float* w     = (const float*)d_in[0];  // pred_weights [256][2048][128]
    const float* price = (const float*)d_in[1];  // price_list   [256][2049][128]
    const int*   psz   = (const int*)d_in[2];    // pred_sz      [256]
    float* out = (float*)d_out;
    float* ws  = (float*)d_ws;

    rp_kernel<<<BS * NCHUNK, 256, 0, stream>>>(w, price, psz, ws);
    final_kernel<<<1, 64, 0, stream>>>(ws, psz, out);
}